// Round 2
// baseline (3037.787 us; speedup 1.0000x reference)
//
#include <hip/hip_runtime.h>
#include <cmath>

// Problem constants
#define LSIG  2097153      // signal / rfft length (= NFFT/2+1)
#define MH    2097152      // NFFT/2 (complex FFT size for packed real trick)
#define NFFTC 4194304      // 2^22
#define NT    262144       // MH/8 = threads per FFT pass
#define O1C   1048577
#define O2C   524289
#define O3C   262145

// Workspace byte offsets
#define A_OFF    0
#define B_OFF    16777216
#define C_OFF    33554432
#define D_OFF    50331656
#define PM_OFF   58720268
#define FEAT_OFF 58720272

struct SmultTab { int hidx[40]; float inv12[40]; int fk[40]; int maxe; };

__device__ __forceinline__ float2 cadd(float2 a, float2 b){ return make_float2(a.x+b.x, a.y+b.y); }
__device__ __forceinline__ float2 csub(float2 a, float2 b){ return make_float2(a.x-b.x, a.y-b.y); }
__device__ __forceinline__ float2 cmul(float2 a, float2 b){ return make_float2(a.x*b.x - a.y*b.y, a.x*b.y + a.y*b.x); }

// multiply by -i (FWD) or +i (INV)
template<bool FWD> __device__ __forceinline__ float2 jrot(float2 z){
  return FWD ? make_float2(z.y, -z.x) : make_float2(-z.y, z.x);
}

// natural-order radix-8 DFT butterfly
template<bool FWD> __device__ __forceinline__ void dft8(float2 v[8]) {
  const float cq = 0.70710678118654752440f;
  const float S  = FWD ? -1.0f : 1.0f;
  float2 e0 = cadd(v[0], v[4]), e1 = csub(v[0], v[4]);
  float2 e2 = cadd(v[2], v[6]), e3 = csub(v[2], v[6]);
  float2 E0 = cadd(e0, e2), E2 = csub(e0, e2);
  float2 jt = jrot<FWD>(e3);
  float2 E1 = cadd(e1, jt), E3 = csub(e1, jt);
  float2 o0 = cadd(v[1], v[5]), o1 = csub(v[1], v[5]);
  float2 o2 = cadd(v[3], v[7]), o3 = csub(v[3], v[7]);
  float2 O0 = cadd(o0, o2), O2 = csub(o0, o2);
  float2 jo = jrot<FWD>(o3);
  float2 O1 = cadd(o1, jo), O3 = csub(o1, jo);
  float2 T1 = make_float2(cq, S*cq), T3 = make_float2(-cq, S*cq);
  float2 w1 = cmul(T1, O1);
  float2 w2 = jrot<FWD>(O2);
  float2 w3 = cmul(T3, O3);
  v[0] = cadd(E0, O0); v[4] = csub(E0, O0);
  v[1] = cadd(E1, w1); v[5] = csub(E1, w1);
  v[2] = cadd(E2, w2); v[6] = csub(E2, w2);
  v[3] = cadd(E3, w3); v[7] = csub(E3, w3);
}

// One Stockham radix-8 pass over MH complex points. 7 passes total (8^7 = 2^21).
template<bool FWD>
__global__ __launch_bounds__(256) void kfft8(const float2* __restrict__ src,
                                             float2* __restrict__ dst, int Ns) {
  int j = blockIdx.x*256 + threadIdx.x;          // j in [0, MH/8)
  int m = j & (Ns - 1);
  float frac = (float)m / (float)(Ns * 8);       // exact (power-of-two denom)
  float th = (FWD ? -6.28318530717958647692f : 6.28318530717958647692f) * frac;
  float2 v[8];
  v[0] = src[j];
#pragma unroll
  for (int r = 1; r < 8; ++r) {
    float2 a = src[j + r*NT];
    float sn, cs;
    sincosf(th * (float)r, &sn, &cs);
    v[r] = make_float2(a.x*cs - a.y*sn, a.x*sn + a.y*cs);
  }
  dft8<FWD>(v);
  int base = ((j - m) << 3) + m;                 // (j/Ns)*Ns*8 + j%Ns
#pragma unroll
  for (int r = 0; r < 8; ++r) dst[base + r*Ns] = v[r];
}

// Pack padded real signal into complex array: z[n] = x[2n] + i x[2n+1]
__global__ __launch_bounds__(256) void kpack(const float* __restrict__ z,
                                             float2* __restrict__ A) {
  int n = blockIdx.x*256 + threadIdx.x;          // n < MH
  float x0 = 0.0f, x1 = 0.0f;
  if (2*n + 1 < LSIG) {
    float2 v = ((const float2*)z)[n];
    x0 = v.x; x1 = v.y;
  } else if (2*n < LSIG) {
    x0 = z[2*n];
  }
  A[n] = make_float2(x0, x1);
}

// prog_mean reduction: sum over i<L of harm_prog[ci].rowsum * (1 + mp1(i)*sin(2pi i/L))
__global__ __launch_bounds__(256) void kprog(
    const float* __restrict__ tw1, const float* __restrict__ tb1,
    const float* __restrict__ tw2, const float* __restrict__ tb2,
    const float* __restrict__ tw3, const float* __restrict__ tb3,
    const float* __restrict__ hp, float* __restrict__ pm) {
  __shared__ float sw1[32], sb1[32], sw2[512], sb2[16], sw3[16], shp[8], sb31[1];
  __shared__ float red[256];
  const int tid = threadIdx.x;
  if (tid < 32) { sw1[tid] = tw1[tid]; sb1[tid] = tb1[tid]; }
  for (int q = tid; q < 512; q += 256) sw2[q] = tw2[q];
  if (tid < 16) { sb2[tid] = tb2[tid]; sw3[tid] = tw3[tid*8+1]; }
  if (tid < 8) { float s = 0.f; for (int j = 0; j < 4; ++j) s += hp[tid*4+j]; shp[tid] = s; }
  if (tid == 0) sb31[0] = tb3[1];
  __syncthreads();
  const int gid = blockIdx.x*256 + tid;          // grid = 2048 blocks -> gid < 524288
  const float Lf = 2097153.0f;
  float tnv[4], sv[4];
  int ci[4];
  float acc[4][16];
#pragma unroll
  for (int e = 0; e < 4; ++e) {
    float ti = (float)(gid + e*524288);
    float tn = ti / Lf;
    tnv[e] = tn;
    sv[e] = sinf((6.28318530717958647692f * ti) / Lf);
    ci[e] = ((int)floorf(tn * 8.0f)) & 7;
#pragma unroll
    for (int kk = 0; kk < 16; ++kk) acc[e][kk] = sb2[kk];
  }
  for (int j = 0; j < 32; ++j) {
    float a = sw1[j], b = sb1[j];
    float hj[4];
#pragma unroll
    for (int e = 0; e < 4; ++e) hj[e] = fmaxf(a*tnv[e] + b, 0.0f);
#pragma unroll
    for (int kk = 0; kk < 16; ++kk) {
      float w = sw2[j*16 + kk];
#pragma unroll
      for (int e = 0; e < 4; ++e) acc[e][kk] += hj[e]*w;
    }
  }
  float lsum = 0.0f;
#pragma unroll
  for (int e = 0; e < 4; ++e) {
    float mp1 = sb31[0];
#pragma unroll
    for (int kk = 0; kk < 16; ++kk) mp1 += fmaxf(acc[e][kk], 0.0f)*sw3[kk];
    lsum += shp[ci[e]] * (1.0f + mp1*sv[e]);
  }
  if (gid == 0) {                                 // tail element i = L-1 = 2097152
    float ti = 2097152.0f;
    float tn = ti / Lf;
    float a1[16];
    for (int kk = 0; kk < 16; ++kk) a1[kk] = sb2[kk];
    for (int j = 0; j < 32; ++j) {
      float h = fmaxf(sw1[j]*tn + sb1[j], 0.0f);
      for (int kk = 0; kk < 16; ++kk) a1[kk] += h*sw2[j*16+kk];
    }
    float mp1 = sb31[0];
    for (int kk = 0; kk < 16; ++kk) mp1 += fmaxf(a1[kk], 0.0f)*sw3[kk];
    float svx = sinf((6.28318530717958647692f * ti) / Lf);
    int cix = ((int)floorf(tn * 8.0f)) & 7;
    lsum += shp[cix] * (1.0f + mp1*svx);
  }
  red[tid] = lsum;
  __syncthreads();
  for (int off = 128; off > 0; off >>= 1) {
    if (tid < off) red[tid] += red[tid+off];
    __syncthreads();
  }
  if (tid == 0) atomicAdd(pm, red[0]);
}

// rfft split + band multipliers + harmonic windows; writes modified spectrum C and |C| into D
__global__ __launch_bounds__(256) void ksplit(const float2* __restrict__ Z,
    float2* __restrict__ C, float* __restrict__ D,
    const float* __restrict__ bwp, const float* __restrict__ fwp,
    const float* __restrict__ pm_in, SmultTab tab) {
  int k = blockIdx.x*256 + threadIdx.x;
  if (k > MH) return;
  float2 zk = Z[k & (MH-1)];
  float2 zm = Z[(MH - k) & (MH-1)];
  float2 s  = make_float2(zk.x + zm.x, zk.y - zm.y);   // Z[k] + conj(Z[M-k])
  float2 dd = make_float2(zk.x - zm.x, zk.y + zm.y);   // Z[k] - conj(Z[M-k])
  float fr = (float)k / (float)NFFTC;
  float sn, cs;
  sincosf(-6.28318530717958647692f * fr, &sn, &cs);    // e^{-2pi i k/N}
  float2 t1 = make_float2(cs*dd.x - sn*dd.y, cs*dd.y + sn*dd.x);
  float2 X  = make_float2(0.5f*(s.x + t1.y), 0.5f*(s.y - t1.x)); // Xe - 0.5 i w d
  float mv = 1.0f;
  if (k <= 38050) {                                    // bands only reach 200 Hz
    const float blo[6] = {1.0f,4.0f,8.0f,13.0f,30.0f,100.0f};
    const float bhi[6] = {4.0f,8.0f,13.0f,30.0f,100.0f,200.0f};
    const float bcn[6] = {2.5f,6.0f,10.5f,21.5f,65.0f,150.0f};
    const float bhw[6] = {0.75f,1.0f,1.25f,4.25f,17.5f,25.0f};
    float f = (float)((double)k * (22050.0/4194304.0));
#pragma unroll
    for (int b = 0; b < 6; ++b) {
      if (f >= blo[b] && f <= bhi[b]) {
        float q = (f - bcn[b]) / bhw[b];
        float mask = expf(-0.5f*q*q);
        double frd = (double)k * ((double)bcn[b] / 22050.0);
        frd -= floor(frd);
        float tm = sinf(6.28318530717958647692f * (float)frd);
        mv *= (1.0f + mask * bwp[b] * (1.0f + 0.2f*tm));
      }
    }
  }
  if (k <= tab.maxe) {
    float pm1 = 1.0f + pm_in[0] * (1.0f/8388612.0f);   // 1 + sum/(L*4)
    for (int w = 0; w < 40; ++w) {
      int dlt = k - tab.hidx[w];
      if (dlt >= -15 && dlt <= 15) {
        float x = (float)dlt * 0.2f;                   // /(WIN/3)=5
        float win = expf(-0.5f*x*x);
        float enh = fwp[tab.fk[w]] * win * tab.inv12[w] * pm1;
        mv *= (1.0f + enh);
      }
    }
  }
  float2 c = make_float2(X.x*mv, X.y*mv);
  C[k] = c;
  D[k] = sqrtf(c.x*c.x + c.y*c.y);
}

__device__ __forceinline__ float2 get_xc(int k, const float2* __restrict__ C,
                                         const float* __restrict__ D) {
  float mg = D[k];
  float ms;
  if (k == 0 || k == MH) ms = mg;
  else ms = 0.7f*mg + 0.15f*D[k-1] + 0.15f*D[k+1];
  float2 c = C[k];
  if (mg > 0.0f) { float sc = ms/mg; return make_float2(c.x*sc, c.y*sc); }
  return make_float2(ms, 0.0f);                        // angle(0)=0 convention
}

// magnitude smoothing + inverse-rfft packing (with 1/M scale folded in)
__global__ __launch_bounds__(256) void ksmooth(const float2* __restrict__ C,
    const float* __restrict__ D, float2* __restrict__ A) {
  int n = blockIdx.x*256 + threadIdx.x;                // n < MH
  float2 a = get_xc(n, C, D);
  float2 b = get_xc(MH - n, C, D);
  float2 s  = make_float2(a.x + b.x, a.y - b.y);       // X + conj(Xm)
  float2 dd = make_float2(a.x - b.x, a.y + b.y);       // X - conj(Xm)
  float fr = (float)n / (float)NFFTC;
  float sn, cs;
  sincosf(6.28318530717958647692f * fr, &sn, &cs);     // e^{+2pi i n/N}
  float2 xo = make_float2(0.5f*(cs*dd.x - sn*dd.y), 0.5f*(cs*dd.y + sn*dd.x));
  const float sc = 1.0f / (float)MH;
  A[n] = make_float2((0.5f*s.x - xo.y)*sc, (0.5f*s.y + xo.x)*sc); // (Xe + i Xo)/M
}

// Fused conv1+conv2+conv3 + per-channel partial sums (one 32-wide o3 tile per block)
__global__ __launch_bounds__(256) void kconv(const float2* __restrict__ z2,
    const float* __restrict__ c1w, const float* __restrict__ c1b,
    const float* __restrict__ c2w, const float* __restrict__ c2b,
    const float* __restrict__ c3w, const float* __restrict__ c3b,
    float* __restrict__ feat) {
  __shared__ float sb[280];
  __shared__ float sh1[32*140];
  __shared__ float sh2[64*68];
  __shared__ float sfin[1024];
  const int tid = threadIdx.x;
  const int blk = blockIdx.x;
  const int s3 = blk * 32;
  // stage base tile: p in [8*s3-14, 8*s3+262]
  {
    int pb = 8*s3 - 14;
    for (int idx = tid; idx < 277; idx += 256) {
      int p = pb + idx;
      float v = 0.0f;
      if (p >= 0 && p < LSIG) {
        float2 e = z2[p >> 1];
        v = (p & 1) ? e.y : e.x;
      }
      sb[idx] = v;
    }
  }
  __syncthreads();
  // h1: 32 ch x 137 positions
  {
    int c1 = tid & 31, g1 = tid >> 5;
    const float* wp = c1w + c1*5;
    float u0 = wp[0], u1 = wp[1], u2 = wp[2], u3 = wp[3], u4 = wp[4];
    float bb = c1b[c1];
    int a1 = 4*s3 - 6;
    for (int q = g1; q < 137; q += 8) {
      int o1 = a1 + q;
      float v = 0.0f;
      if (o1 >= 0 && o1 < O1C) {
        int x = 2*q;
        float aa = bb + u0*sb[x] + u1*sb[x+1] + u2*sb[x+2] + u3*sb[x+3] + u4*sb[x+4];
        v = aa > 0.0f ? aa : 0.2f*aa;
      }
      sh1[c1*140 + q] = v;
    }
  }
  __syncthreads();
  // h2: 64 ch x 67 positions; thread = 4 channels x 5 position-slots
  {
    int c2g = tid & 15, gp = tid >> 4;
    float acc[4][5];
#pragma unroll
    for (int cc = 0; cc < 4; ++cc)
#pragma unroll
      for (int it = 0; it < 5; ++it) acc[cc][it] = 0.0f;
    for (int c1 = 0; c1 < 32; ++c1) {
      const float* wp = c2w + (c2g*4)*160 + c1*5;
      float u[4][5];
#pragma unroll
      for (int cc = 0; cc < 4; ++cc)
#pragma unroll
        for (int t = 0; t < 5; ++t) u[cc][t] = wp[cc*160 + t];
      const float* h1p = sh1 + c1*140;
#pragma unroll
      for (int it = 0; it < 5; ++it) {
        int o2r = gp + 16*it;
        if (o2r < 67) {
          int x = 2*o2r;
          float v0 = h1p[x], v1 = h1p[x+1], v2 = h1p[x+2], v3 = h1p[x+3], v4 = h1p[x+4];
#pragma unroll
          for (int cc = 0; cc < 4; ++cc)
            acc[cc][it] += u[cc][0]*v0 + u[cc][1]*v1 + u[cc][2]*v2 + u[cc][3]*v3 + u[cc][4]*v4;
        }
      }
    }
    int a2 = 2*s3 - 2;
#pragma unroll
    for (int cc = 0; cc < 4; ++cc) {
      int c2 = c2g*4 + cc;
      float bb = c2b[c2];
#pragma unroll
      for (int it = 0; it < 5; ++it) {
        int o2r = gp + 16*it;
        if (o2r < 67) {
          int o2 = a2 + o2r;
          float v = 0.0f;
          if (o2 >= 0 && o2 < O2C) { float aa = acc[cc][it] + bb; v = aa > 0.0f ? aa : 0.2f*aa; }
          sh2[c2*68 + o2r] = v;
        }
      }
    }
  }
  __syncthreads();
  // h3: 128 ch x 32 positions; thread = 4 channels x 4 position-slots
  {
    int c3g = tid & 31, g3 = tid >> 5;
    float acc[4][4];
#pragma unroll
    for (int cc = 0; cc < 4; ++cc)
#pragma unroll
      for (int it = 0; it < 4; ++it) acc[cc][it] = 0.0f;
    for (int c2 = 0; c2 < 64; ++c2) {
      const float* wp = c3w + (c3g*4)*320 + c2*5;
      float u[4][5];
#pragma unroll
      for (int cc = 0; cc < 4; ++cc)
#pragma unroll
        for (int t = 0; t < 5; ++t) u[cc][t] = wp[cc*320 + t];
      const float* h2p = sh2 + c2*68;
#pragma unroll
      for (int it = 0; it < 4; ++it) {
        int r = 2*g3 + 16*it;
        float v0 = h2p[r], v1 = h2p[r+1], v2 = h2p[r+2], v3 = h2p[r+3], v4 = h2p[r+4];
#pragma unroll
        for (int cc = 0; cc < 4; ++cc)
          acc[cc][it] += u[cc][0]*v0 + u[cc][1]*v1 + u[cc][2]*v2 + u[cc][3]*v3 + u[cc][4]*v4;
      }
    }
#pragma unroll
    for (int cc = 0; cc < 4; ++cc) {
      int c3 = c3g*4 + cc;
      float bb = c3b[c3];
      float pch = 0.0f;
#pragma unroll
      for (int it = 0; it < 4; ++it) {
        int o3 = s3 + g3 + 8*it;
        if (o3 < O3C) { float aa = acc[cc][it] + bb; pch += aa > 0.0f ? aa : 0.2f*aa; }
      }
      sfin[c3*8 + g3] = pch;
    }
  }
  __syncthreads();
  if (tid < 128) {
    float tot = 0.0f;
#pragma unroll
    for (int g = 0; g < 8; ++g) tot += sfin[tid*8 + g];
    atomicAdd(&feat[(blk & 255)*128 + tid], tot);
  }
}

// final mean + 2-layer MLP -> one f32 scalar
__global__ __launch_bounds__(256) void kfinal(const float* __restrict__ feat,
    const float* __restrict__ mw1, const float* __restrict__ mb1,
    const float* __restrict__ mw2, const float* __restrict__ mb2,
    float* __restrict__ out) {
  __shared__ float sfeat[128];
  __shared__ float red[256];
  const int tid = threadIdx.x;
  if (tid < 128) {
    float s = 0.0f;
    for (int sl = 0; sl < 256; ++sl) s += feat[sl*128 + tid];
    sfeat[tid] = s / 262145.0f;
  }
  __syncthreads();
  float y = mb1[tid];
  for (int i = 0; i < 128; ++i) y += sfeat[i] * mw1[i*256 + tid];
  y = y > 0.0f ? y : 0.2f*y;
  red[tid] = y * mw2[tid];
  __syncthreads();
  for (int off = 128; off > 0; off >>= 1) {
    if (tid < off) red[tid] += red[tid+off];
    __syncthreads();
  }
  if (tid == 0) out[0] = red[0] + mb2[0];
}

extern "C" void kernel_launch(void* const* d_in, const int* in_sizes, int n_in,
                              void* d_out, int out_size, void* d_ws, size_t ws_size,
                              hipStream_t stream) {
  (void)in_sizes; (void)n_in; (void)out_size; (void)ws_size;
  const float* z   = (const float*)d_in[0];
  const float* bw  = (const float*)d_in[2];
  const float* fw  = (const float*)d_in[3];
  const float* hp  = (const float*)d_in[4];
  const float* tw1 = (const float*)d_in[5];
  const float* tb1 = (const float*)d_in[6];
  const float* tw2 = (const float*)d_in[7];
  const float* tb2 = (const float*)d_in[8];
  const float* tw3 = (const float*)d_in[9];
  const float* tb3 = (const float*)d_in[10];
  const float* c1w = (const float*)d_in[11];
  const float* c1b = (const float*)d_in[12];
  const float* c2w = (const float*)d_in[13];
  const float* c2b = (const float*)d_in[14];
  const float* c3w = (const float*)d_in[15];
  const float* c3b = (const float*)d_in[16];
  const float* mw1 = (const float*)d_in[17];
  const float* mb1 = (const float*)d_in[18];
  const float* mw2 = (const float*)d_in[19];
  const float* mb2 = (const float*)d_in[20];

  char* wsb = (char*)d_ws;
  float2* A    = (float2*)(wsb + A_OFF);
  float2* B    = (float2*)(wsb + B_OFF);
  float2* C    = (float2*)(wsb + C_OFF);
  float*  D    = (float*)(wsb + D_OFF);
  float*  PM   = (float*)(wsb + PM_OFF);
  float*  FEAT = (float*)(wsb + FEAT_OFF);

  // static harmonic-window table (double precision; matches argmin over f32 rfftfreq)
  SmultTab tab;
  {
    const double spec[8] = {7.83, 528.0, 396.0, 2.5, 14.1, 432.0, 6.0, 30.0};
    int n = 0, maxe = 0;
    for (int kk = 0; kk < 8; ++kk)
      for (int m = 1; m <= 5; ++m) {
        double hf = spec[kk] * (double)m;
        if (hf >= 11025.0) continue;
        int hidx = (int)std::floor(hf * (4194304.0/22050.0) + 0.5);
        tab.hidx[n]  = hidx;
        tab.inv12[n] = (float)(1.0/std::pow((double)m, 1.2));
        tab.fk[n]    = kk;
        if (hidx + 15 > maxe) maxe = hidx + 15;
        ++n;
      }
    tab.maxe = maxe;  // n == 40
  }

  hipMemsetAsync(wsb + PM_OFF, 0, 4 + 131072, stream);   // PM + FEAT accumulators
  kprog<<<2048,256,0,stream>>>(tw1,tb1,tw2,tb2,tw3,tb3,hp,PM);
  kpack<<<8192,256,0,stream>>>(z, A);

  float2 *s = A, *d = B;
  int Ns = 1;
  for (int p = 0; p < 7; ++p) {                      // forward cfft (2^21, radix-8 x7)
    kfft8<true><<<1024,256,0,stream>>>(s, d, Ns);
    float2* t = s; s = d; d = t; Ns <<= 3;
  }
  ksplit<<<8193,256,0,stream>>>(s, C, D, bw, fw, PM, tab);
  ksmooth<<<8192,256,0,stream>>>(C, D, A);
  s = A; d = B; Ns = 1;
  for (int p = 0; p < 7; ++p) {                      // inverse cfft
    kfft8<false><<<1024,256,0,stream>>>(s, d, Ns);
    float2* t = s; s = d; d = t; Ns <<= 3;
  }
  kconv<<<8193,256,0,stream>>>(s, c1w, c1b, c2w, c2b, c3w, c3b, FEAT);
  kfinal<<<1,256,0,stream>>>(FEAT, mw1, mb1, mw2, mb2, (float*)d_out);
}

// Round 3
// 1186.322 us; speedup vs baseline: 2.5607x; 2.5607x over previous
//
#include <hip/hip_runtime.h>
#include <cmath>

// Problem constants
#define LSIG  2097153      // signal / rfft length (= NFFT/2+1)
#define MH    2097152      // NFFT/2 (complex FFT size for packed real trick)
#define NFFTC 4194304      // 2^22
#define NT    262144       // MH/8 = threads per FFT pass
#define O1C   1048577
#define O2C   524289
#define O3C   262145

// conv tiling
#define TO3   64           // o3 positions per block
#define NB3   4097         // ceil(O3C/TO3)
#define S1U   134          // sh1 row stride in dwords (bf16 pairs; 133 used)
#define S2C   132          // sh2 row stride in floats (131 used)

// Workspace byte offsets
#define A_OFF    0
#define B_OFF    16777216
#define C_OFF    33554432
#define D_OFF    50331656
#define PM_OFF   58720268
#define FEAT_OFF 58720272

struct SmultTab { int hidx[40]; float inv12[40]; int fk[40]; int maxe; };

__device__ __forceinline__ float2 cadd(float2 a, float2 b){ return make_float2(a.x+b.x, a.y+b.y); }
__device__ __forceinline__ float2 csub(float2 a, float2 b){ return make_float2(a.x-b.x, a.y-b.y); }
__device__ __forceinline__ float2 cmul(float2 a, float2 b){ return make_float2(a.x*b.x - a.y*b.y, a.x*b.y + a.y*b.x); }

// multiply by -i (FWD) or +i (INV)
template<bool FWD> __device__ __forceinline__ float2 jrot(float2 z){
  return FWD ? make_float2(z.y, -z.x) : make_float2(-z.y, z.x);
}

// natural-order radix-8 DFT butterfly
template<bool FWD> __device__ __forceinline__ void dft8(float2 v[8]) {
  const float cq = 0.70710678118654752440f;
  const float S  = FWD ? -1.0f : 1.0f;
  float2 e0 = cadd(v[0], v[4]), e1 = csub(v[0], v[4]);
  float2 e2 = cadd(v[2], v[6]), e3 = csub(v[2], v[6]);
  float2 E0 = cadd(e0, e2), E2 = csub(e0, e2);
  float2 jt = jrot<FWD>(e3);
  float2 E1 = cadd(e1, jt), E3 = csub(e1, jt);
  float2 o0 = cadd(v[1], v[5]), o1 = csub(v[1], v[5]);
  float2 o2 = cadd(v[3], v[7]), o3 = csub(v[3], v[7]);
  float2 O0 = cadd(o0, o2), O2 = csub(o0, o2);
  float2 jo = jrot<FWD>(o3);
  float2 O1 = cadd(o1, jo), O3 = csub(o1, jo);
  float2 T1 = make_float2(cq, S*cq), T3 = make_float2(-cq, S*cq);
  float2 w1 = cmul(T1, O1);
  float2 w2 = jrot<FWD>(O2);
  float2 w3 = cmul(T3, O3);
  v[0] = cadd(E0, O0); v[4] = csub(E0, O0);
  v[1] = cadd(E1, w1); v[5] = csub(E1, w1);
  v[2] = cadd(E2, w2); v[6] = csub(E2, w2);
  v[3] = cadd(E3, w3); v[7] = csub(E3, w3);
}

// One Stockham radix-8 pass over MH complex points. 7 passes total (8^7 = 2^21).
template<bool FWD>
__global__ __launch_bounds__(256) void kfft8(const float2* __restrict__ src,
                                             float2* __restrict__ dst, int Ns) {
  int j = blockIdx.x*256 + threadIdx.x;          // j in [0, MH/8)
  int m = j & (Ns - 1);
  float frac = (float)m / (float)(Ns * 8);       // exact (power-of-two denom)
  float th = (FWD ? -6.28318530717958647692f : 6.28318530717958647692f) * frac;
  float2 v[8];
  v[0] = src[j];
#pragma unroll
  for (int r = 1; r < 8; ++r) {
    float2 a = src[j + r*NT];
    float sn, cs;
    sincosf(th * (float)r, &sn, &cs);
    v[r] = make_float2(a.x*cs - a.y*sn, a.x*sn + a.y*cs);
  }
  dft8<FWD>(v);
  int base = ((j - m) << 3) + m;                 // (j/Ns)*Ns*8 + j%Ns
#pragma unroll
  for (int r = 0; r < 8; ++r) dst[base + r*Ns] = v[r];
}

// Pack padded real signal into complex array: z[n] = x[2n] + i x[2n+1]
__global__ __launch_bounds__(256) void kpack(const float* __restrict__ z,
                                             float2* __restrict__ A) {
  int n = blockIdx.x*256 + threadIdx.x;          // n < MH
  float x0 = 0.0f, x1 = 0.0f;
  if (2*n + 1 < LSIG) {
    float2 v = ((const float2*)z)[n];
    x0 = v.x; x1 = v.y;
  } else if (2*n < LSIG) {
    x0 = z[2*n];
  }
  A[n] = make_float2(x0, x1);
}

// prog_mean reduction
__global__ __launch_bounds__(256) void kprog(
    const float* __restrict__ tw1, const float* __restrict__ tb1,
    const float* __restrict__ tw2, const float* __restrict__ tb2,
    const float* __restrict__ tw3, const float* __restrict__ tb3,
    const float* __restrict__ hp, float* __restrict__ pm) {
  __shared__ float sw1[32], sb1[32], sw2[512], sb2[16], sw3[16], shp[8], sb31[1];
  __shared__ float red[256];
  const int tid = threadIdx.x;
  if (tid < 32) { sw1[tid] = tw1[tid]; sb1[tid] = tb1[tid]; }
  for (int q = tid; q < 512; q += 256) sw2[q] = tw2[q];
  if (tid < 16) { sb2[tid] = tb2[tid]; sw3[tid] = tw3[tid*8+1]; }
  if (tid < 8) { float s = 0.f; for (int j = 0; j < 4; ++j) s += hp[tid*4+j]; shp[tid] = s; }
  if (tid == 0) sb31[0] = tb3[1];
  __syncthreads();
  const int gid = blockIdx.x*256 + tid;          // grid = 2048 blocks -> gid < 524288
  const float Lf = 2097153.0f;
  float tnv[4], sv[4];
  int ci[4];
  float acc[4][16];
#pragma unroll
  for (int e = 0; e < 4; ++e) {
    float ti = (float)(gid + e*524288);
    float tn = ti / Lf;
    tnv[e] = tn;
    sv[e] = sinf((6.28318530717958647692f * ti) / Lf);
    ci[e] = ((int)floorf(tn * 8.0f)) & 7;
#pragma unroll
    for (int kk = 0; kk < 16; ++kk) acc[e][kk] = sb2[kk];
  }
  for (int j = 0; j < 32; ++j) {
    float a = sw1[j], b = sb1[j];
    float hj[4];
#pragma unroll
    for (int e = 0; e < 4; ++e) hj[e] = fmaxf(a*tnv[e] + b, 0.0f);
#pragma unroll
    for (int kk = 0; kk < 16; ++kk) {
      float w = sw2[j*16 + kk];
#pragma unroll
      for (int e = 0; e < 4; ++e) acc[e][kk] += hj[e]*w;
    }
  }
  float lsum = 0.0f;
#pragma unroll
  for (int e = 0; e < 4; ++e) {
    float mp1 = sb31[0];
#pragma unroll
    for (int kk = 0; kk < 16; ++kk) mp1 += fmaxf(acc[e][kk], 0.0f)*sw3[kk];
    lsum += shp[ci[e]] * (1.0f + mp1*sv[e]);
  }
  if (gid == 0) {                                 // tail element i = L-1 = 2097152
    float ti = 2097152.0f;
    float tn = ti / Lf;
    float a1[16];
    for (int kk = 0; kk < 16; ++kk) a1[kk] = sb2[kk];
    for (int j = 0; j < 32; ++j) {
      float h = fmaxf(sw1[j]*tn + sb1[j], 0.0f);
      for (int kk = 0; kk < 16; ++kk) a1[kk] += h*sw2[j*16+kk];
    }
    float mp1 = sb31[0];
    for (int kk = 0; kk < 16; ++kk) mp1 += fmaxf(a1[kk], 0.0f)*sw3[kk];
    float svx = sinf((6.28318530717958647692f * ti) / Lf);
    int cix = ((int)floorf(tn * 8.0f)) & 7;
    lsum += shp[cix] * (1.0f + mp1*svx);
  }
  red[tid] = lsum;
  __syncthreads();
  for (int off = 128; off > 0; off >>= 1) {
    if (tid < off) red[tid] += red[tid+off];
    __syncthreads();
  }
  if (tid == 0) atomicAdd(pm, red[0]);
}

// rfft split + band multipliers + harmonic windows; writes modified spectrum C and |C| into D
__global__ __launch_bounds__(256) void ksplit(const float2* __restrict__ Z,
    float2* __restrict__ C, float* __restrict__ D,
    const float* __restrict__ bwp, const float* __restrict__ fwp,
    const float* __restrict__ pm_in, SmultTab tab) {
  int k = blockIdx.x*256 + threadIdx.x;
  if (k > MH) return;
  float2 zk = Z[k & (MH-1)];
  float2 zm = Z[(MH - k) & (MH-1)];
  float2 s  = make_float2(zk.x + zm.x, zk.y - zm.y);   // Z[k] + conj(Z[M-k])
  float2 dd = make_float2(zk.x - zm.x, zk.y + zm.y);   // Z[k] - conj(Z[M-k])
  float fr = (float)k / (float)NFFTC;
  float sn, cs;
  sincosf(-6.28318530717958647692f * fr, &sn, &cs);    // e^{-2pi i k/N}
  float2 t1 = make_float2(cs*dd.x - sn*dd.y, cs*dd.y + sn*dd.x);
  float2 X  = make_float2(0.5f*(s.x + t1.y), 0.5f*(s.y - t1.x)); // Xe - 0.5 i w d
  float mv = 1.0f;
  if (k <= 38050) {                                    // bands only reach 200 Hz
    const float blo[6] = {1.0f,4.0f,8.0f,13.0f,30.0f,100.0f};
    const float bhi[6] = {4.0f,8.0f,13.0f,30.0f,100.0f,200.0f};
    const float bcn[6] = {2.5f,6.0f,10.5f,21.5f,65.0f,150.0f};
    const float bhw[6] = {0.75f,1.0f,1.25f,4.25f,17.5f,25.0f};
    float f = (float)((double)k * (22050.0/4194304.0));
#pragma unroll
    for (int b = 0; b < 6; ++b) {
      if (f >= blo[b] && f <= bhi[b]) {
        float q = (f - bcn[b]) / bhw[b];
        float mask = expf(-0.5f*q*q);
        double frd = (double)k * ((double)bcn[b] / 22050.0);
        frd -= floor(frd);
        float tm = sinf(6.28318530717958647692f * (float)frd);
        mv *= (1.0f + mask * bwp[b] * (1.0f + 0.2f*tm));
      }
    }
  }
  if (k <= tab.maxe) {
    float pm1 = 1.0f + pm_in[0] * (1.0f/8388612.0f);   // 1 + sum/(L*4)
    for (int w = 0; w < 40; ++w) {
      int dlt = k - tab.hidx[w];
      if (dlt >= -15 && dlt <= 15) {
        float x = (float)dlt * 0.2f;                   // /(WIN/3)=5
        float win = expf(-0.5f*x*x);
        float enh = fwp[tab.fk[w]] * win * tab.inv12[w] * pm1;
        mv *= (1.0f + enh);
      }
    }
  }
  float2 c = make_float2(X.x*mv, X.y*mv);
  C[k] = c;
  D[k] = sqrtf(c.x*c.x + c.y*c.y);
}

__device__ __forceinline__ float2 get_xc(int k, const float2* __restrict__ C,
                                         const float* __restrict__ D) {
  float mg = D[k];
  float ms;
  if (k == 0 || k == MH) ms = mg;
  else ms = 0.7f*mg + 0.15f*D[k-1] + 0.15f*D[k+1];
  float2 c = C[k];
  if (mg > 0.0f) { float sc = ms/mg; return make_float2(c.x*sc, c.y*sc); }
  return make_float2(ms, 0.0f);                        // angle(0)=0 convention
}

// magnitude smoothing + inverse-rfft packing (with 1/M scale folded in)
__global__ __launch_bounds__(256) void ksmooth(const float2* __restrict__ C,
    const float* __restrict__ D, float2* __restrict__ A) {
  int n = blockIdx.x*256 + threadIdx.x;                // n < MH
  float2 a = get_xc(n, C, D);
  float2 b = get_xc(MH - n, C, D);
  float2 s  = make_float2(a.x + b.x, a.y - b.y);       // X + conj(Xm)
  float2 dd = make_float2(a.x - b.x, a.y + b.y);       // X - conj(Xm)
  float fr = (float)n / (float)NFFTC;
  float sn, cs;
  sincosf(6.28318530717958647692f * fr, &sn, &cs);     // e^{+2pi i n/N}
  float2 xo = make_float2(0.5f*(cs*dd.x - sn*dd.y), 0.5f*(cs*dd.y + sn*dd.x));
  const float sc = 1.0f / (float)MH;
  A[n] = make_float2((0.5f*s.x - xo.y)*sc, (0.5f*s.y + xo.x)*sc); // (Xe + i Xo)/M
}

// bf16 pack/unpack helpers (h1 stored as packed bf16 pairs)
__device__ __forceinline__ unsigned int rbf(float f) {
  unsigned int u = __float_as_uint(f);
  u += 0x7fffu + ((u >> 16) & 1u);
  return u >> 16;
}
__device__ __forceinline__ unsigned int pack_bf2(float a, float b) {
  return rbf(a) | (rbf(b) << 16);
}
__device__ __forceinline__ float ublo(unsigned int u){ return __uint_as_float(u << 16); }
__device__ __forceinline__ float ubhi(unsigned int u){ return __uint_as_float(u & 0xffff0000u); }

// Fused conv1+conv2+conv3 + per-channel partial sums.
// 64 o3 positions per block; lane = position; channel = f(wave) -> weights wave-uniform (s_load).
__global__ __launch_bounds__(256) void kconv(const float* __restrict__ x,
    const float* __restrict__ c1w, const float* __restrict__ c1b,
    const float* __restrict__ c2w, const float* __restrict__ c2b,
    const float* __restrict__ c3w, const float* __restrict__ c3b,
    float* __restrict__ feat) {
  __shared__ float sb[536];                 // base tile (533 used)
  __shared__ unsigned int sh1u[32*S1U];     // h1, bf16 pairs (133 dwords/row used)
  __shared__ float sh2[64*S2C];             // h2 fp32 (131/row used)
  const int tid = threadIdx.x;
  const int blk = blockIdx.x;
  const int s3 = blk * TO3;

  // stage base: local idx -> global 8*s3-14+idx
  {
    const int pb = 8*s3 - 14;
    for (int idx = tid; idx < 536; idx += 256) {
      int p = pb + idx;
      sb[idx] = (idx < 533 && p >= 0 && p < LSIG) ? x[p] : 0.0f;
    }
  }
  __syncthreads();

  // conv1: 32 ch x 265 positions, two positions per iteration, packed bf16x2
  {
    const int c1 = tid & 31, g = tid >> 5;
    const float u0=c1w[c1*5+0], u1=c1w[c1*5+1], u2=c1w[c1*5+2], u3=c1w[c1*5+3], u4=c1w[c1*5+4];
    const float bb = c1b[c1];
    const int a1 = 4*s3 - 6;
    for (int j = g; j < 133; j += 8) {
      float v0=sb[4*j+0],v1=sb[4*j+1],v2=sb[4*j+2],v3=sb[4*j+3],v4=sb[4*j+4],v5=sb[4*j+5],v6=sb[4*j+6];
      float r0 = 0.f, r1 = 0.f;
      int o0 = a1 + 2*j;
      if (o0 >= 0 && o0 < O1C) {
        float aa = bb + u0*v0+u1*v1+u2*v2+u3*v3+u4*v4; r0 = aa>0.f?aa:0.2f*aa;
      }
      if (o0+1 >= 0 && o0+1 < O1C && 2*j+1 < 265) {
        float aa = bb + u0*v2+u1*v3+u2*v4+u3*v5+u4*v6; r1 = aa>0.f?aa:0.2f*aa;
      }
      sh1u[c1*S1U + j] = pack_bf2(r0, r1);
    }
  }
  __syncthreads();

  // conv2: 64 out-ch x 131 positions; wave -> 16 channels (2 groups of 8), lane -> position
  {
    const int w = __builtin_amdgcn_readfirstlane(tid >> 6);
    const int lane = tid & 63;
    const int a2 = 2*s3 - 2;
#pragma unroll
    for (int pi = 0; pi < 3; ++pi) {
      const int p = lane + pi*64;               // local o2 position
      if (p < 131) {
        const unsigned int* hp = sh1u + p;
#pragma unroll
        for (int gg = 0; gg < 2; ++gg) {
          const int ch0 = w*16 + gg*8;
          float acc[8];
#pragma unroll
          for (int cc = 0; cc < 8; ++cc) acc[cc] = 0.0f;
          for (int c1 = 0; c1 < 32; ++c1) {
            unsigned int q0 = hp[c1*S1U+0], q1 = hp[c1*S1U+1], q2 = hp[c1*S1U+2];
            float v0=ublo(q0), v1=ubhi(q0), v2=ublo(q1), v3=ubhi(q1), v4=ublo(q2);
            const float* wp = c2w + ch0*160 + c1*5;   // wave-uniform address
#pragma unroll
            for (int cc = 0; cc < 8; ++cc)
              acc[cc] += wp[cc*160+0]*v0 + wp[cc*160+1]*v1 + wp[cc*160+2]*v2
                       + wp[cc*160+3]*v3 + wp[cc*160+4]*v4;
          }
          int o2 = a2 + p;
          bool ok = (o2 >= 0 && o2 < O2C);
#pragma unroll
          for (int cc = 0; cc < 8; ++cc) {
            float aa = acc[cc] + c2b[ch0+cc];
            sh2[(ch0+cc)*S2C + p] = ok ? (aa>0.f?aa:0.2f*aa) : 0.0f;
          }
        }
      }
    }
  }
  __syncthreads();

  // conv3: 128 out-ch x 64 positions; wave -> 32 channels (4 groups of 8), lane -> position
  {
    const int w = __builtin_amdgcn_readfirstlane(tid >> 6);
    const int lane = tid & 63;
    const int o3 = s3 + lane;
    const bool ok3 = (o3 < O3C);
    const int slot = (blk & 255) * 128;
#pragma unroll
    for (int gg = 0; gg < 4; ++gg) {
      const int ch = w*32 + gg*8;
      float acc[8];
#pragma unroll
      for (int cc = 0; cc < 8; ++cc) acc[cc] = 0.0f;
      for (int c2 = 0; c2 < 64; ++c2) {
        const float* hp = sh2 + c2*S2C + 2*lane;
        float v0=hp[0], v1=hp[1], v2=hp[2], v3=hp[3], v4=hp[4];
        const float* wp = c3w + ch*320 + c2*5;        // wave-uniform address
#pragma unroll
        for (int cc = 0; cc < 8; ++cc)
          acc[cc] += wp[cc*320+0]*v0 + wp[cc*320+1]*v1 + wp[cc*320+2]*v2
                   + wp[cc*320+3]*v3 + wp[cc*320+4]*v4;
      }
#pragma unroll
      for (int cc = 0; cc < 8; ++cc) {
        float aa = acc[cc] + c3b[ch+cc];
        float v = ok3 ? (aa>0.f?aa:0.2f*aa) : 0.0f;
        v += __shfl_down(v, 32);
        v += __shfl_down(v, 16);
        v += __shfl_down(v, 8);
        v += __shfl_down(v, 4);
        v += __shfl_down(v, 2);
        v += __shfl_down(v, 1);
        if (lane == 0) atomicAdd(&feat[slot + ch + cc], v);
      }
    }
  }
}

// final mean + 2-layer MLP -> one f32 scalar
__global__ __launch_bounds__(256) void kfinal(const float* __restrict__ feat,
    const float* __restrict__ mw1, const float* __restrict__ mb1,
    const float* __restrict__ mw2, const float* __restrict__ mb2,
    float* __restrict__ out) {
  __shared__ float sfeat[128];
  __shared__ float red[256];
  const int tid = threadIdx.x;
  if (tid < 128) {
    float s = 0.0f;
    for (int sl = 0; sl < 256; ++sl) s += feat[sl*128 + tid];
    sfeat[tid] = s / 262145.0f;
  }
  __syncthreads();
  float y = mb1[tid];
  for (int i = 0; i < 128; ++i) y += sfeat[i] * mw1[i*256 + tid];
  y = y > 0.0f ? y : 0.2f*y;
  red[tid] = y * mw2[tid];
  __syncthreads();
  for (int off = 128; off > 0; off >>= 1) {
    if (tid < off) red[tid] += red[tid+off];
    __syncthreads();
  }
  if (tid == 0) out[0] = red[0] + mb2[0];
}

extern "C" void kernel_launch(void* const* d_in, const int* in_sizes, int n_in,
                              void* d_out, int out_size, void* d_ws, size_t ws_size,
                              hipStream_t stream) {
  (void)in_sizes; (void)n_in; (void)out_size; (void)ws_size;
  const float* z   = (const float*)d_in[0];
  const float* bw  = (const float*)d_in[2];
  const float* fw  = (const float*)d_in[3];
  const float* hp  = (const float*)d_in[4];
  const float* tw1 = (const float*)d_in[5];
  const float* tb1 = (const float*)d_in[6];
  const float* tw2 = (const float*)d_in[7];
  const float* tb2 = (const float*)d_in[8];
  const float* tw3 = (const float*)d_in[9];
  const float* tb3 = (const float*)d_in[10];
  const float* c1w = (const float*)d_in[11];
  const float* c1b = (const float*)d_in[12];
  const float* c2w = (const float*)d_in[13];
  const float* c2b = (const float*)d_in[14];
  const float* c3w = (const float*)d_in[15];
  const float* c3b = (const float*)d_in[16];
  const float* mw1 = (const float*)d_in[17];
  const float* mb1 = (const float*)d_in[18];
  const float* mw2 = (const float*)d_in[19];
  const float* mb2 = (const float*)d_in[20];

  char* wsb = (char*)d_ws;
  float2* A    = (float2*)(wsb + A_OFF);
  float2* B    = (float2*)(wsb + B_OFF);
  float2* C    = (float2*)(wsb + C_OFF);
  float*  D    = (float*)(wsb + D_OFF);
  float*  PM   = (float*)(wsb + PM_OFF);
  float*  FEAT = (float*)(wsb + FEAT_OFF);

  // static harmonic-window table
  SmultTab tab;
  {
    const double spec[8] = {7.83, 528.0, 396.0, 2.5, 14.1, 432.0, 6.0, 30.0};
    int n = 0, maxe = 0;
    for (int kk = 0; kk < 8; ++kk)
      for (int m = 1; m <= 5; ++m) {
        double hf = spec[kk] * (double)m;
        if (hf >= 11025.0) continue;
        int hidx = (int)std::floor(hf * (4194304.0/22050.0) + 0.5);
        tab.hidx[n]  = hidx;
        tab.inv12[n] = (float)(1.0/std::pow((double)m, 1.2));
        tab.fk[n]    = kk;
        if (hidx + 15 > maxe) maxe = hidx + 15;
        ++n;
      }
    tab.maxe = maxe;  // n == 40
  }

  hipMemsetAsync(wsb + PM_OFF, 0, 4 + 131072, stream);   // PM + FEAT accumulators
  kprog<<<2048,256,0,stream>>>(tw1,tb1,tw2,tb2,tw3,tb3,hp,PM);
  kpack<<<8192,256,0,stream>>>(z, A);

  float2 *s = A, *d = B;
  int Ns = 1;
  for (int p = 0; p < 7; ++p) {                      // forward cfft (2^21, radix-8 x7)
    kfft8<true><<<1024,256,0,stream>>>(s, d, Ns);
    float2* t = s; s = d; d = t; Ns <<= 3;
  }
  ksplit<<<8193,256,0,stream>>>(s, C, D, bw, fw, PM, tab);
  ksmooth<<<8192,256,0,stream>>>(C, D, A);
  s = A; d = B; Ns = 1;
  for (int p = 0; p < 7; ++p) {                      // inverse cfft
    kfft8<false><<<1024,256,0,stream>>>(s, d, Ns);
    float2* t = s; s = d; d = t; Ns <<= 3;
  }
  kconv<<<NB3,256,0,stream>>>((const float*)s, c1w, c1b, c2w, c2b, c3w, c3b, FEAT);
  kfinal<<<1,256,0,stream>>>(FEAT, mw1, mb1, mw2, mb2, (float*)d_out);
}

// Round 4
// 1154.184 us; speedup vs baseline: 2.6320x; 1.0278x over previous
//
#include <hip/hip_runtime.h>
#include <cmath>

// Problem constants
#define LSIG  2097153      // signal / rfft length (= NFFT/2+1)
#define MH    2097152      // NFFT/2 (complex FFT size for packed real trick)
#define NFFTC 4194304      // 2^22
#define NT    262144       // MH/8 = threads per FFT pass
#define O1C   1048577
#define O2C   524289
#define O3C   262145

// conv tiling: 128 o3 positions per block
#define TO3   128
#define NB3   2049         // ceil(O3C/TO3)
#define S1U   262          // sh1 row stride in dwords (bf16 pairs; 261 used)
#define S2U   131          // sh2 row stride in dwords (bf16 pairs; 130 used)

// Workspace byte offsets
#define A_OFF    0
#define B_OFF    16777216
#define C_OFF    33554432
#define D_OFF    50331656
#define PM_OFF   58720268
#define FEAT_OFF 58720272

struct SmultTab { int hidx[40]; float inv12[40]; int fk[40]; int maxe; };

__device__ __forceinline__ float2 cadd(float2 a, float2 b){ return make_float2(a.x+b.x, a.y+b.y); }
__device__ __forceinline__ float2 csub(float2 a, float2 b){ return make_float2(a.x-b.x, a.y-b.y); }
__device__ __forceinline__ float2 cmul(float2 a, float2 b){ return make_float2(a.x*b.x - a.y*b.y, a.x*b.y + a.y*b.x); }

// multiply by -i (FWD) or +i (INV)
template<bool FWD> __device__ __forceinline__ float2 jrot(float2 z){
  return FWD ? make_float2(z.y, -z.x) : make_float2(-z.y, z.x);
}

// natural-order radix-8 DFT butterfly
template<bool FWD> __device__ __forceinline__ void dft8(float2 v[8]) {
  const float cq = 0.70710678118654752440f;
  const float S  = FWD ? -1.0f : 1.0f;
  float2 e0 = cadd(v[0], v[4]), e1 = csub(v[0], v[4]);
  float2 e2 = cadd(v[2], v[6]), e3 = csub(v[2], v[6]);
  float2 E0 = cadd(e0, e2), E2 = csub(e0, e2);
  float2 jt = jrot<FWD>(e3);
  float2 E1 = cadd(e1, jt), E3 = csub(e1, jt);
  float2 o0 = cadd(v[1], v[5]), o1 = csub(v[1], v[5]);
  float2 o2 = cadd(v[3], v[7]), o3 = csub(v[3], v[7]);
  float2 O0 = cadd(o0, o2), O2 = csub(o0, o2);
  float2 jo = jrot<FWD>(o3);
  float2 O1 = cadd(o1, jo), O3 = csub(o1, jo);
  float2 T1 = make_float2(cq, S*cq), T3 = make_float2(-cq, S*cq);
  float2 w1 = cmul(T1, O1);
  float2 w2 = jrot<FWD>(O2);
  float2 w3 = cmul(T3, O3);
  v[0] = cadd(E0, O0); v[4] = csub(E0, O0);
  v[1] = cadd(E1, w1); v[5] = csub(E1, w1);
  v[2] = cadd(E2, w2); v[6] = csub(E2, w2);
  v[3] = cadd(E3, w3); v[7] = csub(E3, w3);
}

// One Stockham radix-8 pass over MH complex points. 7 passes total (8^7 = 2^21).
template<bool FWD>
__global__ __launch_bounds__(256) void kfft8(const float2* __restrict__ src,
                                             float2* __restrict__ dst, int Ns) {
  int j = blockIdx.x*256 + threadIdx.x;          // j in [0, MH/8)
  int m = j & (Ns - 1);
  float frac = (float)m / (float)(Ns * 8);       // exact (power-of-two denom)
  float th = (FWD ? -6.28318530717958647692f : 6.28318530717958647692f) * frac;
  float2 v[8];
  v[0] = src[j];
#pragma unroll
  for (int r = 1; r < 8; ++r) {
    float2 a = src[j + r*NT];
    float sn, cs;
    sincosf(th * (float)r, &sn, &cs);
    v[r] = make_float2(a.x*cs - a.y*sn, a.x*sn + a.y*cs);
  }
  dft8<FWD>(v);
  int base = ((j - m) << 3) + m;                 // (j/Ns)*Ns*8 + j%Ns
#pragma unroll
  for (int r = 0; r < 8; ++r) dst[base + r*Ns] = v[r];
}

// Pack padded real signal into complex array: z[n] = x[2n] + i x[2n+1]
__global__ __launch_bounds__(256) void kpack(const float* __restrict__ z,
                                             float2* __restrict__ A) {
  int n = blockIdx.x*256 + threadIdx.x;          // n < MH
  float x0 = 0.0f, x1 = 0.0f;
  if (2*n + 1 < LSIG) {
    float2 v = ((const float2*)z)[n];
    x0 = v.x; x1 = v.y;
  } else if (2*n < LSIG) {
    x0 = z[2*n];
  }
  A[n] = make_float2(x0, x1);
}

// prog_mean reduction
__global__ __launch_bounds__(256) void kprog(
    const float* __restrict__ tw1, const float* __restrict__ tb1,
    const float* __restrict__ tw2, const float* __restrict__ tb2,
    const float* __restrict__ tw3, const float* __restrict__ tb3,
    const float* __restrict__ hp, float* __restrict__ pm) {
  __shared__ float sw1[32], sb1[32], sw2[512], sb2[16], sw3[16], shp[8], sb31[1];
  __shared__ float red[256];
  const int tid = threadIdx.x;
  if (tid < 32) { sw1[tid] = tw1[tid]; sb1[tid] = tb1[tid]; }
  for (int q = tid; q < 512; q += 256) sw2[q] = tw2[q];
  if (tid < 16) { sb2[tid] = tb2[tid]; sw3[tid] = tw3[tid*8+1]; }
  if (tid < 8) { float s = 0.f; for (int j = 0; j < 4; ++j) s += hp[tid*4+j]; shp[tid] = s; }
  if (tid == 0) sb31[0] = tb3[1];
  __syncthreads();
  const int gid = blockIdx.x*256 + tid;          // grid = 2048 blocks -> gid < 524288
  const float Lf = 2097153.0f;
  float tnv[4], sv[4];
  int ci[4];
  float acc[4][16];
#pragma unroll
  for (int e = 0; e < 4; ++e) {
    float ti = (float)(gid + e*524288);
    float tn = ti / Lf;
    tnv[e] = tn;
    sv[e] = sinf((6.28318530717958647692f * ti) / Lf);
    ci[e] = ((int)floorf(tn * 8.0f)) & 7;
#pragma unroll
    for (int kk = 0; kk < 16; ++kk) acc[e][kk] = sb2[kk];
  }
  for (int j = 0; j < 32; ++j) {
    float a = sw1[j], b = sb1[j];
    float hj[4];
#pragma unroll
    for (int e = 0; e < 4; ++e) hj[e] = fmaxf(a*tnv[e] + b, 0.0f);
#pragma unroll
    for (int kk = 0; kk < 16; ++kk) {
      float w = sw2[j*16 + kk];
#pragma unroll
      for (int e = 0; e < 4; ++e) acc[e][kk] += hj[e]*w;
    }
  }
  float lsum = 0.0f;
#pragma unroll
  for (int e = 0; e < 4; ++e) {
    float mp1 = sb31[0];
#pragma unroll
    for (int kk = 0; kk < 16; ++kk) mp1 += fmaxf(acc[e][kk], 0.0f)*sw3[kk];
    lsum += shp[ci[e]] * (1.0f + mp1*sv[e]);
  }
  if (gid == 0) {                                 // tail element i = L-1 = 2097152
    float ti = 2097152.0f;
    float tn = ti / Lf;
    float a1[16];
    for (int kk = 0; kk < 16; ++kk) a1[kk] = sb2[kk];
    for (int j = 0; j < 32; ++j) {
      float h = fmaxf(sw1[j]*tn + sb1[j], 0.0f);
      for (int kk = 0; kk < 16; ++kk) a1[kk] += h*sw2[j*16+kk];
    }
    float mp1 = sb31[0];
    for (int kk = 0; kk < 16; ++kk) mp1 += fmaxf(a1[kk], 0.0f)*sw3[kk];
    float svx = sinf((6.28318530717958647692f * ti) / Lf);
    int cix = ((int)floorf(tn * 8.0f)) & 7;
    lsum += shp[cix] * (1.0f + mp1*svx);
  }
  red[tid] = lsum;
  __syncthreads();
  for (int off = 128; off > 0; off >>= 1) {
    if (tid < off) red[tid] += red[tid+off];
    __syncthreads();
  }
  if (tid == 0) atomicAdd(pm, red[0]);
}

// rfft split + band multipliers + harmonic windows; writes modified spectrum C and |C| into D
__global__ __launch_bounds__(256) void ksplit(const float2* __restrict__ Z,
    float2* __restrict__ C, float* __restrict__ D,
    const float* __restrict__ bwp, const float* __restrict__ fwp,
    const float* __restrict__ pm_in, SmultTab tab) {
  int k = blockIdx.x*256 + threadIdx.x;
  if (k > MH) return;
  float2 zk = Z[k & (MH-1)];
  float2 zm = Z[(MH - k) & (MH-1)];
  float2 s  = make_float2(zk.x + zm.x, zk.y - zm.y);   // Z[k] + conj(Z[M-k])
  float2 dd = make_float2(zk.x - zm.x, zk.y + zm.y);   // Z[k] - conj(Z[M-k])
  float fr = (float)k / (float)NFFTC;
  float sn, cs;
  sincosf(-6.28318530717958647692f * fr, &sn, &cs);    // e^{-2pi i k/N}
  float2 t1 = make_float2(cs*dd.x - sn*dd.y, cs*dd.y + sn*dd.x);
  float2 X  = make_float2(0.5f*(s.x + t1.y), 0.5f*(s.y - t1.x)); // Xe - 0.5 i w d
  float mv = 1.0f;
  if (k <= 38050) {                                    // bands only reach 200 Hz
    const float blo[6] = {1.0f,4.0f,8.0f,13.0f,30.0f,100.0f};
    const float bhi[6] = {4.0f,8.0f,13.0f,30.0f,100.0f,200.0f};
    const float bcn[6] = {2.5f,6.0f,10.5f,21.5f,65.0f,150.0f};
    const float bhw[6] = {0.75f,1.0f,1.25f,4.25f,17.5f,25.0f};
    float f = (float)((double)k * (22050.0/4194304.0));
#pragma unroll
    for (int b = 0; b < 6; ++b) {
      if (f >= blo[b] && f <= bhi[b]) {
        float q = (f - bcn[b]) / bhw[b];
        float mask = expf(-0.5f*q*q);
        double frd = (double)k * ((double)bcn[b] / 22050.0);
        frd -= floor(frd);
        float tm = sinf(6.28318530717958647692f * (float)frd);
        mv *= (1.0f + mask * bwp[b] * (1.0f + 0.2f*tm));
      }
    }
  }
  if (k <= tab.maxe) {
    float pm1 = 1.0f + pm_in[0] * (1.0f/8388612.0f);   // 1 + sum/(L*4)
    for (int w = 0; w < 40; ++w) {
      int dlt = k - tab.hidx[w];
      if (dlt >= -15 && dlt <= 15) {
        float x = (float)dlt * 0.2f;                   // /(WIN/3)=5
        float win = expf(-0.5f*x*x);
        float enh = fwp[tab.fk[w]] * win * tab.inv12[w] * pm1;
        mv *= (1.0f + enh);
      }
    }
  }
  float2 c = make_float2(X.x*mv, X.y*mv);
  C[k] = c;
  D[k] = sqrtf(c.x*c.x + c.y*c.y);
}

__device__ __forceinline__ float2 get_xc(int k, const float2* __restrict__ C,
                                         const float* __restrict__ D) {
  float mg = D[k];
  float ms;
  if (k == 0 || k == MH) ms = mg;
  else ms = 0.7f*mg + 0.15f*D[k-1] + 0.15f*D[k+1];
  float2 c = C[k];
  if (mg > 0.0f) { float sc = ms/mg; return make_float2(c.x*sc, c.y*sc); }
  return make_float2(ms, 0.0f);                        // angle(0)=0 convention
}

// magnitude smoothing + inverse-rfft packing (with 1/M scale folded in)
__global__ __launch_bounds__(256) void ksmooth(const float2* __restrict__ C,
    const float* __restrict__ D, float2* __restrict__ A) {
  int n = blockIdx.x*256 + threadIdx.x;                // n < MH
  float2 a = get_xc(n, C, D);
  float2 b = get_xc(MH - n, C, D);
  float2 s  = make_float2(a.x + b.x, a.y - b.y);       // X + conj(Xm)
  float2 dd = make_float2(a.x - b.x, a.y + b.y);       // X - conj(Xm)
  float fr = (float)n / (float)NFFTC;
  float sn, cs;
  sincosf(6.28318530717958647692f * fr, &sn, &cs);     // e^{+2pi i n/N}
  float2 xo = make_float2(0.5f*(cs*dd.x - sn*dd.y), 0.5f*(cs*dd.y + sn*dd.x));
  const float sc = 1.0f / (float)MH;
  A[n] = make_float2((0.5f*s.x - xo.y)*sc, (0.5f*s.y + xo.x)*sc); // (Xe + i Xo)/M
}

// bf16 pack/unpack helpers
__device__ __forceinline__ unsigned int rbf(float f) {
  unsigned int u = __float_as_uint(f);
  u += 0x7fffu + ((u >> 16) & 1u);
  return u >> 16;
}
__device__ __forceinline__ unsigned int pack_bf2(float a, float b) {
  return rbf(a) | (rbf(b) << 16);
}
__device__ __forceinline__ float ublo(unsigned int u){ return __uint_as_float(u << 16); }
__device__ __forceinline__ float ubhi(unsigned int u){ return __uint_as_float(u & 0xffff0000u); }
__device__ __forceinline__ float lrelu(float a){ return a > 0.0f ? a : 0.2f*a; }

// Fused conv1+conv2+conv3 + per-channel partial sums.
// 128 o3 positions per block. lane = position slot (stride-64), wave = channel group.
// Weights hoisted to wave-uniform scalar loads reused across all position slots.
__global__ __launch_bounds__(256) void kconv(const float* __restrict__ x,
    const float* __restrict__ c1w, const float* __restrict__ c1b,
    const float* __restrict__ c2w, const float* __restrict__ c2b,
    const float* __restrict__ c3w, const float* __restrict__ c3b,
    float* __restrict__ feat) {
  __shared__ float sb[1048];                // base tile (1045 used)
  __shared__ unsigned int sh1u[32*S1U];     // h1, bf16 pairs (261 dw/row used)
  __shared__ unsigned int sh2u[64*S2U];     // h2, bf16 pairs (130 dw/row used)
  const int tid  = threadIdx.x;
  const int blk  = blockIdx.x;
  const int s3   = blk * TO3;
  const int lane = tid & 63;
  const int w    = __builtin_amdgcn_readfirstlane(tid >> 6);

  // stage base: local idx -> global 8*s3-14+idx
  {
    const int pb = 8*s3 - 14;
    for (int idx = tid; idx < 1048; idx += 256) {
      int p = pb + idx;
      sb[idx] = (idx < 1045 && p >= 0 && p < LSIG) ? x[p] : 0.0f;
    }
  }
  __syncthreads();

  // conv1: 32 ch x 521 positions (261 bf16-pair dwords per row)
  {
    const int c1 = tid & 31, g = tid >> 5;
    const float u0=c1w[c1*5+0], u1=c1w[c1*5+1], u2=c1w[c1*5+2], u3=c1w[c1*5+3], u4=c1w[c1*5+4];
    const float bb = c1b[c1];
    const int a1 = 4*s3 - 6;
    for (int j = g; j <= 260; j += 8) {
      float v0=sb[4*j+0],v1=sb[4*j+1],v2=sb[4*j+2],v3=sb[4*j+3],v4=sb[4*j+4],v5=sb[4*j+5],v6=sb[4*j+6];
      float r0 = 0.f, r1 = 0.f;
      int o0 = a1 + 2*j;
      if (o0 >= 0 && o0 < O1C)
        r0 = lrelu(bb + u0*v0+u1*v1+u2*v2+u3*v3+u4*v4);
      if (2*j+1 <= 520 && o0+1 >= 0 && o0+1 < O1C)
        r1 = lrelu(bb + u0*v2+u1*v3+u2*v4+u3*v5+u4*v6);
      sh1u[c1*S1U + j] = pack_bf2(r0, r1);
    }
  }
  __syncthreads();

  // conv2: 64 out-ch x 259 positions; wave -> 16 ch (2 groups of 8); lane -> 5 position slots
  {
    const int a2 = 2*s3 - 2;
    unsigned short* sh2s = (unsigned short*)sh2u;
    for (int gg = 0; gg < 2; ++gg) {
      const int ch0 = w*16 + gg*8;
      float acc[8][5];
#pragma unroll
      for (int cc = 0; cc < 8; ++cc)
#pragma unroll
        for (int pi = 0; pi < 5; ++pi) acc[cc][pi] = 0.0f;
      for (int c1 = 0; c1 < 32; ++c1) {
        float wv[8][5];
#pragma unroll
        for (int cc = 0; cc < 8; ++cc)
#pragma unroll
          for (int t = 0; t < 5; ++t) wv[cc][t] = c2w[(ch0+cc)*160 + c1*5 + t];  // wave-uniform -> SGPR
        const unsigned int* hrow = sh1u + c1*S1U;
#pragma unroll
        for (int pi = 0; pi < 5; ++pi) {
          const int p = lane + 64*pi;
          if (p < 259) {
            unsigned int q0 = hrow[p], q1 = hrow[p+1], q2 = hrow[p+2];
            float v0=ubhi(q0)==0.f?ublo(q0):ublo(q0);  // (no-op guard removed below)
            v0=ublo(q0); float v1=ubhi(q0), v2=ublo(q1), v3=ubhi(q1), v4=ublo(q2);
#pragma unroll
            for (int cc = 0; cc < 8; ++cc)
              acc[cc][pi] += wv[cc][0]*v0 + wv[cc][1]*v1 + wv[cc][2]*v2
                           + wv[cc][3]*v3 + wv[cc][4]*v4;
          }
        }
      }
#pragma unroll
      for (int cc = 0; cc < 8; ++cc) {
        const int ch = ch0 + cc;
        const float bb = c2b[ch];
#pragma unroll
        for (int pi = 0; pi < 5; ++pi) {
          const int p = lane + 64*pi;
          if (p < 259) {
            int o2 = a2 + p;
            float aa = acc[cc][pi] + bb;
            float h = (o2 >= 0 && o2 < O2C) ? lrelu(aa) : 0.0f;
            sh2s[ch*(2*S2U) + p] = (unsigned short)rbf(h);
          }
        }
      }
    }
  }
  __syncthreads();

  // conv3: 128 out-ch x 128 positions; wave -> 32 ch (4 groups of 8); lane -> 2 position slots
  {
    const int o3a = s3 + lane;
    const int o3b = o3a + 64;
    const bool ma = (o3a < O3C), mb = (o3b < O3C);
    const int slot = (blk & 255) * 128;
    for (int gg = 0; gg < 4; ++gg) {
      const int ch0 = w*32 + gg*8;
      float acc[8][2];
#pragma unroll
      for (int cc = 0; cc < 8; ++cc) { acc[cc][0] = 0.0f; acc[cc][1] = 0.0f; }
      for (int c2 = 0; c2 < 64; ++c2) {
        float wv[8][5];
#pragma unroll
        for (int cc = 0; cc < 8; ++cc)
#pragma unroll
          for (int t = 0; t < 5; ++t) wv[cc][t] = c3w[(ch0+cc)*320 + c2*5 + t];  // wave-uniform -> SGPR
        const unsigned int* hrow = sh2u + c2*S2U;
#pragma unroll
        for (int pi = 0; pi < 2; ++pi) {
          const int p = lane + 64*pi;                   // always < 128, reads <= dword 129
          unsigned int q0 = hrow[p], q1 = hrow[p+1], q2 = hrow[p+2];
          float v0=ublo(q0), v1=ubhi(q0), v2=ublo(q1), v3=ubhi(q1), v4=ublo(q2);
#pragma unroll
          for (int cc = 0; cc < 8; ++cc)
            acc[cc][pi] += wv[cc][0]*v0 + wv[cc][1]*v1 + wv[cc][2]*v2
                         + wv[cc][3]*v3 + wv[cc][4]*v4;
        }
      }
#pragma unroll
      for (int cc = 0; cc < 8; ++cc) {
        const float bb = c3b[ch0+cc];
        float v = (ma ? lrelu(acc[cc][0] + bb) : 0.0f)
                + (mb ? lrelu(acc[cc][1] + bb) : 0.0f);
        v += __shfl_down(v, 32);
        v += __shfl_down(v, 16);
        v += __shfl_down(v, 8);
        v += __shfl_down(v, 4);
        v += __shfl_down(v, 2);
        v += __shfl_down(v, 1);
        if (lane == 0) atomicAdd(&feat[slot + ch0 + cc], v);
      }
    }
  }
}

// final mean + 2-layer MLP -> one f32 scalar
__global__ __launch_bounds__(256) void kfinal(const float* __restrict__ feat,
    const float* __restrict__ mw1, const float* __restrict__ mb1,
    const float* __restrict__ mw2, const float* __restrict__ mb2,
    float* __restrict__ out) {
  __shared__ float sfeat[128];
  __shared__ float red[256];
  const int tid = threadIdx.x;
  if (tid < 128) {
    float s = 0.0f;
    for (int sl = 0; sl < 256; ++sl) s += feat[sl*128 + tid];
    sfeat[tid] = s / 262145.0f;
  }
  __syncthreads();
  float y = mb1[tid];
  for (int i = 0; i < 128; ++i) y += sfeat[i] * mw1[i*256 + tid];
  y = y > 0.0f ? y : 0.2f*y;
  red[tid] = y * mw2[tid];
  __syncthreads();
  for (int off = 128; off > 0; off >>= 1) {
    if (tid < off) red[tid] += red[tid+off];
    __syncthreads();
  }
  if (tid == 0) out[0] = red[0] + mb2[0];
}

extern "C" void kernel_launch(void* const* d_in, const int* in_sizes, int n_in,
                              void* d_out, int out_size, void* d_ws, size_t ws_size,
                              hipStream_t stream) {
  (void)in_sizes; (void)n_in; (void)out_size; (void)ws_size;
  const float* z   = (const float*)d_in[0];
  const float* bw  = (const float*)d_in[2];
  const float* fw  = (const float*)d_in[3];
  const float* hp  = (const float*)d_in[4];
  const float* tw1 = (const float*)d_in[5];
  const float* tb1 = (const float*)d_in[6];
  const float* tw2 = (const float*)d_in[7];
  const float* tb2 = (const float*)d_in[8];
  const float* tw3 = (const float*)d_in[9];
  const float* tb3 = (const float*)d_in[10];
  const float* c1w = (const float*)d_in[11];
  const float* c1b = (const float*)d_in[12];
  const float* c2w = (const float*)d_in[13];
  const float* c2b = (const float*)d_in[14];
  const float* c3w = (const float*)d_in[15];
  const float* c3b = (const float*)d_in[16];
  const float* mw1 = (const float*)d_in[17];
  const float* mb1 = (const float*)d_in[18];
  const float* mw2 = (const float*)d_in[19];
  const float* mb2 = (const float*)d_in[20];

  char* wsb = (char*)d_ws;
  float2* A    = (float2*)(wsb + A_OFF);
  float2* B    = (float2*)(wsb + B_OFF);
  float2* C    = (float2*)(wsb + C_OFF);
  float*  D    = (float*)(wsb + D_OFF);
  float*  PM   = (float*)(wsb + PM_OFF);
  float*  FEAT = (float*)(wsb + FEAT_OFF);

  // static harmonic-window table
  SmultTab tab;
  {
    const double spec[8] = {7.83, 528.0, 396.0, 2.5, 14.1, 432.0, 6.0, 30.0};
    int n = 0, maxe = 0;
    for (int kk = 0; kk < 8; ++kk)
      for (int m = 1; m <= 5; ++m) {
        double hf = spec[kk] * (double)m;
        if (hf >= 11025.0) continue;
        int hidx = (int)std::floor(hf * (4194304.0/22050.0) + 0.5);
        tab.hidx[n]  = hidx;
        tab.inv12[n] = (float)(1.0/std::pow((double)m, 1.2));
        tab.fk[n]    = kk;
        if (hidx + 15 > maxe) maxe = hidx + 15;
        ++n;
      }
    tab.maxe = maxe;  // n == 40
  }

  hipMemsetAsync(wsb + PM_OFF, 0, 4 + 131072, stream);   // PM + FEAT accumulators
  kprog<<<2048,256,0,stream>>>(tw1,tb1,tw2,tb2,tw3,tb3,hp,PM);
  kpack<<<8192,256,0,stream>>>(z, A);

  float2 *s = A, *d = B;
  int Ns = 1;
  for (int p = 0; p < 7; ++p) {                      // forward cfft (2^21, radix-8 x7)
    kfft8<true><<<1024,256,0,stream>>>(s, d, Ns);
    float2* t = s; s = d; d = t; Ns <<= 3;
  }
  ksplit<<<8193,256,0,stream>>>(s, C, D, bw, fw, PM, tab);
  ksmooth<<<8192,256,0,stream>>>(C, D, A);
  s = A; d = B; Ns = 1;
  for (int p = 0; p < 7; ++p) {                      // inverse cfft
    kfft8<false><<<1024,256,0,stream>>>(s, d, Ns);
    float2* t = s; s = d; d = t; Ns <<= 3;
  }
  kconv<<<NB3,256,0,stream>>>((const float*)s, c1w, c1b, c2w, c2b, c3w, c3b, FEAT);
  kfinal<<<1,256,0,stream>>>(FEAT, mw1, mb1, mw2, mb2, (float*)d_out);
}

// Round 6
// 681.322 us; speedup vs baseline: 4.4587x; 1.6940x over previous
//
#include <hip/hip_runtime.h>
#include <cmath>

// Problem constants
#define LSIG  2097153      // signal / rfft length (= NFFT/2+1)
#define MH    2097152      // NFFT/2 (complex FFT size for packed real trick)
#define NFFTC 4194304      // 2^22
#define NT    262144       // MH/8 = threads per FFT pass
#define O1C   1048577
#define O2C   524289
#define O3C   262145

// conv tiling: 62 o3 positions per block (conv2 = 127 pos = 2 full lane slots)
#define TO3   62
#define NB3   4229         // ceil(O3C/TO3)
#define S1DW  130          // sh1 row stride in dwords (f16 pairs; 129 used)
#define S2DW  66           // sh2 row stride in dwords (f16 pairs; 64 used + pad)

// Workspace byte offsets
#define A_OFF    0
#define B_OFF    16777216
#define C_OFF    33554432
#define D_OFF    50331656
#define PM_OFF   58720268
#define FEAT_OFF 58720272
#define W2P_OFF  58851344  // packed f16 conv2 weights: 32*64*3 dwords
#define W3P_OFF  58875920  // packed f16 conv3 weights: 64*128*3 dwords

struct SmultTab { int hidx[40]; float inv12[40]; int fk[40]; int maxe; };

typedef _Float16 h2v __attribute__((ext_vector_type(2)));
typedef __fp16  p2v __attribute__((ext_vector_type(2)));   // cvt_pkrtz return type

__device__ __forceinline__ h2v asn(unsigned int u) {
  union { unsigned int x; h2v h; } c; c.x = u; return c.h;
}
__device__ __forceinline__ unsigned int pkh(float a, float b) {
  p2v h = __builtin_amdgcn_cvt_pkrtz(a, b);
  union { p2v h; unsigned int x; } c; c.h = h; return c.x;
}
__device__ __forceinline__ float lrelu(float a){ return a > 0.0f ? a : 0.2f*a; }

__device__ __forceinline__ float2 cadd(float2 a, float2 b){ return make_float2(a.x+b.x, a.y+b.y); }
__device__ __forceinline__ float2 csub(float2 a, float2 b){ return make_float2(a.x-b.x, a.y-b.y); }
__device__ __forceinline__ float2 cmul(float2 a, float2 b){ return make_float2(a.x*b.x - a.y*b.y, a.x*b.y + a.y*b.x); }

// multiply by -i (FWD) or +i (INV)
template<bool FWD> __device__ __forceinline__ float2 jrot(float2 z){
  return FWD ? make_float2(z.y, -z.x) : make_float2(-z.y, z.x);
}

// natural-order radix-8 DFT butterfly
template<bool FWD> __device__ __forceinline__ void dft8(float2 v[8]) {
  const float cq = 0.70710678118654752440f;
  const float S  = FWD ? -1.0f : 1.0f;
  float2 e0 = cadd(v[0], v[4]), e1 = csub(v[0], v[4]);
  float2 e2 = cadd(v[2], v[6]), e3 = csub(v[2], v[6]);
  float2 E0 = cadd(e0, e2), E2 = csub(e0, e2);
  float2 jt = jrot<FWD>(e3);
  float2 E1 = cadd(e1, jt), E3 = csub(e1, jt);
  float2 o0 = cadd(v[1], v[5]), o1 = csub(v[1], v[5]);
  float2 o2 = cadd(v[3], v[7]), o3 = csub(v[3], v[7]);
  float2 O0 = cadd(o0, o2), O2 = csub(o0, o2);
  float2 jo = jrot<FWD>(o3);
  float2 O1 = cadd(o1, jo), O3 = csub(o1, jo);
  float2 T1 = make_float2(cq, S*cq), T3 = make_float2(-cq, S*cq);
  float2 w1 = cmul(T1, O1);
  float2 w2 = jrot<FWD>(O2);
  float2 w3 = cmul(T3, O3);
  v[0] = cadd(E0, O0); v[4] = csub(E0, O0);
  v[1] = cadd(E1, w1); v[5] = csub(E1, w1);
  v[2] = cadd(E2, w2); v[6] = csub(E2, w2);
  v[3] = cadd(E3, w3); v[7] = csub(E3, w3);
}

// One Stockham radix-8 pass over MH complex points. 7 passes total (8^7 = 2^21).
template<bool FWD>
__global__ __launch_bounds__(256) void kfft8(const float2* __restrict__ src,
                                             float2* __restrict__ dst, int Ns) {
  int j = blockIdx.x*256 + threadIdx.x;          // j in [0, MH/8)
  int m = j & (Ns - 1);
  float frac = (float)m / (float)(Ns * 8);       // exact (power-of-two denom)
  float th = (FWD ? -6.28318530717958647692f : 6.28318530717958647692f) * frac;
  float2 v[8];
  v[0] = src[j];
#pragma unroll
  for (int r = 1; r < 8; ++r) {
    float2 a = src[j + r*NT];
    float sn, cs;
    sincosf(th * (float)r, &sn, &cs);
    v[r] = make_float2(a.x*cs - a.y*sn, a.x*sn + a.y*cs);
  }
  dft8<FWD>(v);
  int base = ((j - m) << 3) + m;                 // (j/Ns)*Ns*8 + j%Ns
#pragma unroll
  for (int r = 0; r < 8; ++r) dst[base + r*Ns] = v[r];
}

// Pack padded real signal into complex array: z[n] = x[2n] + i x[2n+1]
__global__ __launch_bounds__(256) void kpack(const float* __restrict__ z,
                                             float2* __restrict__ A) {
  int n = blockIdx.x*256 + threadIdx.x;          // n < MH
  float x0 = 0.0f, x1 = 0.0f;
  if (2*n + 1 < LSIG) {
    float2 v = ((const float2*)z)[n];
    x0 = v.x; x1 = v.y;
  } else if (2*n < LSIG) {
    x0 = z[2*n];
  }
  A[n] = make_float2(x0, x1);
}

// Convert conv2/conv3 weights to packed-f16 dot2 layout:
// W2P[(c1*64+ch)*3 + {01,23,4_}]  W3P[(c2*128+ch)*3 + {01,23,4_}]
__global__ __launch_bounds__(256) void kwpack(const float* __restrict__ c2w,
    const float* __restrict__ c3w, unsigned int* __restrict__ w2p,
    unsigned int* __restrict__ w3p) {
  int i = blockIdx.x*256 + threadIdx.x;
  if (i < 2048) {                      // conv2: c1 in [0,32), ch in [0,64)
    int c1 = i >> 6, ch = i & 63;
    const float* b = c2w + ch*160 + c1*5;
    w2p[i*3+0] = pkh(b[0], b[1]);
    w2p[i*3+1] = pkh(b[2], b[3]);
    w2p[i*3+2] = pkh(b[4], 0.0f);
  } else if (i < 10240) {              // conv3: c2 in [0,64), ch in [0,128)
    int j = i - 2048;
    int c2 = j >> 7, ch = j & 127;
    const float* b = c3w + ch*320 + c2*5;
    w3p[j*3+0] = pkh(b[0], b[1]);
    w3p[j*3+1] = pkh(b[2], b[3]);
    w3p[j*3+2] = pkh(b[4], 0.0f);
  }
}

// prog_mean reduction
__global__ __launch_bounds__(256) void kprog(
    const float* __restrict__ tw1, const float* __restrict__ tb1,
    const float* __restrict__ tw2, const float* __restrict__ tb2,
    const float* __restrict__ tw3, const float* __restrict__ tb3,
    const float* __restrict__ hp, float* __restrict__ pm) {
  __shared__ float sw1[32], sb1[32], sw2[512], sb2[16], sw3[16], shp[8], sb31[1];
  __shared__ float red[256];
  const int tid = threadIdx.x;
  if (tid < 32) { sw1[tid] = tw1[tid]; sb1[tid] = tb1[tid]; }
  for (int q = tid; q < 512; q += 256) sw2[q] = tw2[q];
  if (tid < 16) { sb2[tid] = tb2[tid]; sw3[tid] = tw3[tid*8+1]; }
  if (tid < 8) { float s = 0.f; for (int j = 0; j < 4; ++j) s += hp[tid*4+j]; shp[tid] = s; }
  if (tid == 0) sb31[0] = tb3[1];
  __syncthreads();
  const int gid = blockIdx.x*256 + tid;          // grid = 2048 blocks -> gid < 524288
  const float Lf = 2097153.0f;
  float tnv[4], sv[4];
  int ci[4];
  float acc[4][16];
#pragma unroll
  for (int e = 0; e < 4; ++e) {
    float ti = (float)(gid + e*524288);
    float tn = ti / Lf;
    tnv[e] = tn;
    sv[e] = sinf((6.28318530717958647692f * ti) / Lf);
    ci[e] = ((int)floorf(tn * 8.0f)) & 7;
#pragma unroll
    for (int kk = 0; kk < 16; ++kk) acc[e][kk] = sb2[kk];
  }
  for (int j = 0; j < 32; ++j) {
    float a = sw1[j], b = sb1[j];
    float hj[4];
#pragma unroll
    for (int e = 0; e < 4; ++e) hj[e] = fmaxf(a*tnv[e] + b, 0.0f);
#pragma unroll
    for (int kk = 0; kk < 16; ++kk) {
      float w = sw2[j*16 + kk];
#pragma unroll
      for (int e = 0; e < 4; ++e) acc[e][kk] += hj[e]*w;
    }
  }
  float lsum = 0.0f;
#pragma unroll
  for (int e = 0; e < 4; ++e) {
    float mp1 = sb31[0];
#pragma unroll
    for (int kk = 0; kk < 16; ++kk) mp1 += fmaxf(acc[e][kk], 0.0f)*sw3[kk];
    lsum += shp[ci[e]] * (1.0f + mp1*sv[e]);
  }
  if (gid == 0) {                                 // tail element i = L-1 = 2097152
    float ti = 2097152.0f;
    float tn = ti / Lf;
    float a1[16];
    for (int kk = 0; kk < 16; ++kk) a1[kk] = sb2[kk];
    for (int j = 0; j < 32; ++j) {
      float h = fmaxf(sw1[j]*tn + sb1[j], 0.0f);
      for (int kk = 0; kk < 16; ++kk) a1[kk] += h*sw2[j*16+kk];
    }
    float mp1 = sb31[0];
    for (int kk = 0; kk < 16; ++kk) mp1 += fmaxf(a1[kk], 0.0f)*sw3[kk];
    float svx = sinf((6.28318530717958647692f * ti) / Lf);
    int cix = ((int)floorf(tn * 8.0f)) & 7;
    lsum += shp[cix] * (1.0f + mp1*svx);
  }
  red[tid] = lsum;
  __syncthreads();
  for (int off = 128; off > 0; off >>= 1) {
    if (tid < off) red[tid] += red[tid+off];
    __syncthreads();
  }
  if (tid == 0) atomicAdd(pm, red[0]);
}

// rfft split + band multipliers + harmonic windows; writes modified spectrum C and |C| into D
__global__ __launch_bounds__(256) void ksplit(const float2* __restrict__ Z,
    float2* __restrict__ C, float* __restrict__ D,
    const float* __restrict__ bwp, const float* __restrict__ fwp,
    const float* __restrict__ pm_in, SmultTab tab) {
  int k = blockIdx.x*256 + threadIdx.x;
  if (k > MH) return;
  float2 zk = Z[k & (MH-1)];
  float2 zm = Z[(MH - k) & (MH-1)];
  float2 s  = make_float2(zk.x + zm.x, zk.y - zm.y);   // Z[k] + conj(Z[M-k])
  float2 dd = make_float2(zk.x - zm.x, zk.y + zm.y);   // Z[k] - conj(Z[M-k])
  float fr = (float)k / (float)NFFTC;
  float sn, cs;
  sincosf(-6.28318530717958647692f * fr, &sn, &cs);    // e^{-2pi i k/N}
  float2 t1 = make_float2(cs*dd.x - sn*dd.y, cs*dd.y + sn*dd.x);
  float2 X  = make_float2(0.5f*(s.x + t1.y), 0.5f*(s.y - t1.x)); // Xe - 0.5 i w d
  float mv = 1.0f;
  if (k <= 38050) {                                    // bands only reach 200 Hz
    const float blo[6] = {1.0f,4.0f,8.0f,13.0f,30.0f,100.0f};
    const float bhi[6] = {4.0f,8.0f,13.0f,30.0f,100.0f,200.0f};
    const float bcn[6] = {2.5f,6.0f,10.5f,21.5f,65.0f,150.0f};
    const float bhw[6] = {0.75f,1.0f,1.25f,4.25f,17.5f,25.0f};
    float f = (float)((double)k * (22050.0/4194304.0));
#pragma unroll
    for (int b = 0; b < 6; ++b) {
      if (f >= blo[b] && f <= bhi[b]) {
        float q = (f - bcn[b]) / bhw[b];
        float mask = expf(-0.5f*q*q);
        double frd = (double)k * ((double)bcn[b] / 22050.0);
        frd -= floor(frd);
        float tm = sinf(6.28318530717958647692f * (float)frd);
        mv *= (1.0f + mask * bwp[b] * (1.0f + 0.2f*tm));
      }
    }
  }
  if (k <= tab.maxe) {
    float pm1 = 1.0f + pm_in[0] * (1.0f/8388612.0f);   // 1 + sum/(L*4)
    for (int w = 0; w < 40; ++w) {
      int dlt = k - tab.hidx[w];
      if (dlt >= -15 && dlt <= 15) {
        float x = (float)dlt * 0.2f;                   // /(WIN/3)=5
        float win = expf(-0.5f*x*x);
        float enh = fwp[tab.fk[w]] * win * tab.inv12[w] * pm1;
        mv *= (1.0f + enh);
      }
    }
  }
  float2 c = make_float2(X.x*mv, X.y*mv);
  C[k] = c;
  D[k] = sqrtf(c.x*c.x + c.y*c.y);
}

__device__ __forceinline__ float2 get_xc(int k, const float2* __restrict__ C,
                                         const float* __restrict__ D) {
  float mg = D[k];
  float ms;
  if (k == 0 || k == MH) ms = mg;
  else ms = 0.7f*mg + 0.15f*D[k-1] + 0.15f*D[k+1];
  float2 c = C[k];
  if (mg > 0.0f) { float sc = ms/mg; return make_float2(c.x*sc, c.y*sc); }
  return make_float2(ms, 0.0f);                        // angle(0)=0 convention
}

// magnitude smoothing + inverse-rfft packing (with 1/M scale folded in)
__global__ __launch_bounds__(256) void ksmooth(const float2* __restrict__ C,
    const float* __restrict__ D, float2* __restrict__ A) {
  int n = blockIdx.x*256 + threadIdx.x;                // n < MH
  float2 a = get_xc(n, C, D);
  float2 b = get_xc(MH - n, C, D);
  float2 s  = make_float2(a.x + b.x, a.y - b.y);       // X + conj(Xm)
  float2 dd = make_float2(a.x - b.x, a.y + b.y);       // X - conj(Xm)
  float fr = (float)n / (float)NFFTC;
  float sn, cs;
  sincosf(6.28318530717958647692f * fr, &sn, &cs);     // e^{+2pi i n/N}
  float2 xo = make_float2(0.5f*(cs*dd.x - sn*dd.y), 0.5f*(cs*dd.y + sn*dd.x));
  const float sc = 1.0f / (float)MH;
  A[n] = make_float2((0.5f*s.x - xo.y)*sc, (0.5f*s.y + xo.x)*sc); // (Xe + i Xo)/M
}

// Fused conv1+conv2+conv3 + per-channel partial sums.
// TO3=62 o3 positions per block: conv2 = 127 positions = 2 full lane slots.
// Activations packed f16 pairs in LDS; weights packed f16 (dot2 layout, SGPR);
// inner dot = 3x v_dot2_f32_f16 per 5-tap/channel.
__global__ __launch_bounds__(256, 4) void kconv(const float* __restrict__ x,
    const unsigned int* __restrict__ w2p, const unsigned int* __restrict__ w3p,
    const float* __restrict__ c1w, const float* __restrict__ c1b,
    const float* __restrict__ c2b, const float* __restrict__ c3b,
    float* __restrict__ feat) {
  __shared__ float sb[520];                 // base tile (517 used)
  __shared__ unsigned int sh1u[32*S1DW];    // h1, f16 pairs (129 dw/row used)
  __shared__ unsigned int sh2u[64*S2DW];    // h2, f16 pairs (64 dw/row used)
  const int tid  = threadIdx.x;
  const int blk  = blockIdx.x;
  const int s3   = blk * TO3;
  const int lane = tid & 63;
  const int w    = __builtin_amdgcn_readfirstlane(tid >> 6);

  // stage base: local idx -> global 8*s3-14+idx
  {
    const int pb = 8*s3 - 14;
    for (int idx = tid; idx < 520; idx += 256) {
      int p = pb + idx;
      sb[idx] = (idx < 517 && p >= 0 && p < LSIG) ? x[p] : 0.0f;
    }
  }
  __syncthreads();

  // conv1: 32 ch x 257 positions -> f16 pairs (129 dwords/row)
  {
    const int c1 = tid & 31, g = tid >> 5;
    const float u0=c1w[c1*5+0], u1=c1w[c1*5+1], u2=c1w[c1*5+2], u3=c1w[c1*5+3], u4=c1w[c1*5+4];
    const float bb = c1b[c1];
    const int a1 = 4*s3 - 6;
    for (int j = g; j <= 128; j += 8) {
      float v0=sb[4*j+0],v1=sb[4*j+1],v2=sb[4*j+2],v3=sb[4*j+3],v4=sb[4*j+4],v5=sb[4*j+5],v6=sb[4*j+6];
      float r0 = 0.f, r1 = 0.f;
      int o0 = a1 + 2*j;
      if (o0 >= 0 && o0 < O1C)
        r0 = lrelu(bb + u0*v0+u1*v1+u2*v2+u3*v3+u4*v4);
      if (j < 128 && o0+1 >= 0 && o0+1 < O1C)
        r1 = lrelu(bb + u0*v2+u1*v3+u2*v4+u3*v5+u4*v6);
      sh1u[c1*S1DW + j] = pkh(r0, r1);
    }
  }
  __syncthreads();

  // conv2: 64 out-ch x 127 positions; wave -> 16 ch (2 groups of 8); lane -> 2 slots
  {
    const int a2 = 2*s3 - 2;
    _Float16* sh2h = (_Float16*)sh2u;
    for (int gg = 0; gg < 2; ++gg) {
      const int ch0 = w*16 + gg*8;
      float acc[8][2];
#pragma unroll
      for (int cc = 0; cc < 8; ++cc) { acc[cc][0] = 0.0f; acc[cc][1] = 0.0f; }
      for (int c1 = 0; c1 < 32; ++c1) {
        const unsigned int* wd = w2p + (unsigned)(c1*64 + ch0)*3;   // wave-uniform
        unsigned int wk[24];
#pragma unroll
        for (int d = 0; d < 24; ++d) wk[d] = wd[d];
        const unsigned int* hrow = sh1u + c1*S1DW;
#pragma unroll
        for (int pi = 0; pi < 2; ++pi) {
          const int p = lane + 64*pi;                 // 0..127 (p=127 lane masked at store)
          unsigned int q0 = hrow[p], q1 = hrow[p+1], q2 = hrow[p+2];
          h2v h0 = asn(q0), h1 = asn(q1), h2 = asn(q2);
#pragma unroll
          for (int cc = 0; cc < 8; ++cc) {
            float a = acc[cc][pi];
            a = __builtin_amdgcn_fdot2(asn(wk[cc*3+0]), h0, a, false);
            a = __builtin_amdgcn_fdot2(asn(wk[cc*3+1]), h1, a, false);
            a = __builtin_amdgcn_fdot2(asn(wk[cc*3+2]), h2, a, false);
            acc[cc][pi] = a;
          }
        }
      }
#pragma unroll
      for (int cc = 0; cc < 8; ++cc) {
        const int ch = ch0 + cc;
        const float bb = c2b[ch];
#pragma unroll
        for (int pi = 0; pi < 2; ++pi) {
          const int p = lane + 64*pi;
          if (p < 127) {
            int o2 = a2 + p;
            float aa = acc[cc][pi] + bb;
            float h = (o2 >= 0 && o2 < O2C) ? lrelu(aa) : 0.0f;
            sh2h[ch*(2*S2DW) + p] = (_Float16)h;
          }
        }
      }
    }
  }
  __syncthreads();

  // conv3: 128 out-ch x 62 positions; wave -> 32 ch (4 groups of 8); lane -> 1 slot
  {
    const int o3 = s3 + lane;
    const bool ok3 = (lane < TO3) && (o3 < O3C);
    const int slot = (blk & 255) * 128;
    for (int gg = 0; gg < 4; ++gg) {
      const int ch0 = w*32 + gg*8;
      float acc[8];
#pragma unroll
      for (int cc = 0; cc < 8; ++cc) acc[cc] = 0.0f;
      for (int c2 = 0; c2 < 64; ++c2) {
        const unsigned int* wd = w3p + (unsigned)(c2*128 + ch0)*3;  // wave-uniform
        unsigned int wk[24];
#pragma unroll
        for (int d = 0; d < 24; ++d) wk[d] = wd[d];
        const unsigned int* hrow = sh2u + c2*S2DW;
        unsigned int q0 = hrow[lane], q1 = hrow[lane+1], q2 = hrow[lane+2];
        h2v h0 = asn(q0), h1 = asn(q1), h2 = asn(q2);
#pragma unroll
        for (int cc = 0; cc < 8; ++cc) {
          float a = acc[cc];
          a = __builtin_amdgcn_fdot2(asn(wk[cc*3+0]), h0, a, false);
          a = __builtin_amdgcn_fdot2(asn(wk[cc*3+1]), h1, a, false);
          a = __builtin_amdgcn_fdot2(asn(wk[cc*3+2]), h2, a, false);
          acc[cc] = a;
        }
      }
#pragma unroll
      for (int cc = 0; cc < 8; ++cc) {
        float v = ok3 ? lrelu(acc[cc] + c3b[ch0+cc]) : 0.0f;
        v += __shfl_down(v, 32);
        v += __shfl_down(v, 16);
        v += __shfl_down(v, 8);
        v += __shfl_down(v, 4);
        v += __shfl_down(v, 2);
        v += __shfl_down(v, 1);
        if (lane == 0) atomicAdd(&feat[slot + ch0 + cc], v);
      }
    }
  }
}

// final mean + 2-layer MLP -> one f32 scalar
__global__ __launch_bounds__(256) void kfinal(const float* __restrict__ feat,
    const float* __restrict__ mw1, const float* __restrict__ mb1,
    const float* __restrict__ mw2, const float* __restrict__ mb2,
    float* __restrict__ out) {
  __shared__ float sfeat[128];
  __shared__ float red[256];
  const int tid = threadIdx.x;
  if (tid < 128) {
    float s = 0.0f;
    for (int sl = 0; sl < 256; ++sl) s += feat[sl*128 + tid];
    sfeat[tid] = s / 262145.0f;
  }
  __syncthreads();
  float y = mb1[tid];
  for (int i = 0; i < 128; ++i) y += sfeat[i] * mw1[i*256 + tid];
  y = y > 0.0f ? y : 0.2f*y;
  red[tid] = y * mw2[tid];
  __syncthreads();
  for (int off = 128; off > 0; off >>= 1) {
    if (tid < off) red[tid] += red[tid+off];
    __syncthreads();
  }
  if (tid == 0) out[0] = red[0] + mb2[0];
}

extern "C" void kernel_launch(void* const* d_in, const int* in_sizes, int n_in,
                              void* d_out, int out_size, void* d_ws, size_t ws_size,
                              hipStream_t stream) {
  (void)in_sizes; (void)n_in; (void)out_size; (void)ws_size;
  const float* z   = (const float*)d_in[0];
  const float* bw  = (const float*)d_in[2];
  const float* fw  = (const float*)d_in[3];
  const float* hp  = (const float*)d_in[4];
  const float* tw1 = (const float*)d_in[5];
  const float* tb1 = (const float*)d_in[6];
  const float* tw2 = (const float*)d_in[7];
  const float* tb2 = (const float*)d_in[8];
  const float* tw3 = (const float*)d_in[9];
  const float* tb3 = (const float*)d_in[10];
  const float* c1w = (const float*)d_in[11];
  const float* c1b = (const float*)d_in[12];
  const float* c2w = (const float*)d_in[13];
  const float* c2b = (const float*)d_in[14];
  const float* c3w = (const float*)d_in[15];
  const float* c3b = (const float*)d_in[16];
  const float* mw1 = (const float*)d_in[17];
  const float* mb1 = (const float*)d_in[18];
  const float* mw2 = (const float*)d_in[19];
  const float* mb2 = (const float*)d_in[20];

  char* wsb = (char*)d_ws;
  float2* A    = (float2*)(wsb + A_OFF);
  float2* B    = (float2*)(wsb + B_OFF);
  float2* C    = (float2*)(wsb + C_OFF);
  float*  D    = (float*)(wsb + D_OFF);
  float*  PM   = (float*)(wsb + PM_OFF);
  float*  FEAT = (float*)(wsb + FEAT_OFF);
  unsigned int* W2P = (unsigned int*)(wsb + W2P_OFF);
  unsigned int* W3P = (unsigned int*)(wsb + W3P_OFF);

  // static harmonic-window table
  SmultTab tab;
  {
    const double spec[8] = {7.83, 528.0, 396.0, 2.5, 14.1, 432.0, 6.0, 30.0};
    int n = 0, maxe = 0;
    for (int kk = 0; kk < 8; ++kk)
      for (int m = 1; m <= 5; ++m) {
        double hf = spec[kk] * (double)m;
        if (hf >= 11025.0) continue;
        int hidx = (int)std::floor(hf * (4194304.0/22050.0) + 0.5);
        tab.hidx[n]  = hidx;
        tab.inv12[n] = (float)(1.0/std::pow((double)m, 1.2));
        tab.fk[n]    = kk;
        if (hidx + 15 > maxe) maxe = hidx + 15;
        ++n;
      }
    tab.maxe = maxe;  // n == 40
  }

  (void)hipMemsetAsync(wsb + PM_OFF, 0, 4 + 131072, stream);   // PM + FEAT accumulators
  kwpack<<<40,256,0,stream>>>(c2w, c3w, W2P, W3P);
  kprog<<<2048,256,0,stream>>>(tw1,tb1,tw2,tb2,tw3,tb3,hp,PM);
  kpack<<<8192,256,0,stream>>>(z, A);

  float2 *s = A, *d = B;
  int Ns = 1;
  for (int p = 0; p < 7; ++p) {                      // forward cfft (2^21, radix-8 x7)
    kfft8<true><<<1024,256,0,stream>>>(s, d, Ns);
    float2* t = s; s = d; d = t; Ns <<= 3;
  }
  ksplit<<<8193,256,0,stream>>>(s, C, D, bw, fw, PM, tab);
  ksmooth<<<8192,256,0,stream>>>(C, D, A);
  s = A; d = B; Ns = 1;
  for (int p = 0; p < 7; ++p) {                      // inverse cfft
    kfft8<false><<<1024,256,0,stream>>>(s, d, Ns);
    float2* t = s; s = d; d = t; Ns <<= 3;
  }
  kconv<<<NB3,256,0,stream>>>((const float*)s, W2P, W3P, c1w, c1b, c2b, c3b, FEAT);
  kfinal<<<1,256,0,stream>>>(FEAT, mw1, mb1, mw2, mb2, (float*)d_out);
}